// Round 8
// baseline (557.309 us; speedup 1.0000x reference)
//
#include <hip/hip_runtime.h>
#include <hip/hip_bf16.h>

typedef __bf16 bf16x8 __attribute__((ext_vector_type(8)));
typedef __bf16 bf16x4 __attribute__((ext_vector_type(4)));
typedef float  f32x4  __attribute__((ext_vector_type(4)));

constexpr int Ee = 8, Cc = 512, Mm = 1024, Hh = 4096, Tt = 2048;

// async global->LDS, 16B/lane. LDS dest wave-uniform base + lane*16 (m97/m104).
__device__ __forceinline__ void async16(void* lds, const void* g) {
  __builtin_amdgcn_global_load_lds(
      (const __attribute__((address_space(1))) void*)g,
      (__attribute__((address_space(3))) void*)lds, 16, 0, 0);
}

#define FENCE() asm volatile("" ::: "memory")
#define BARRIER() do { FENCE(); __builtin_amdgcn_s_barrier(); FENCE(); } while (0)

// Bijective XCD-chunked swizzle (m204).
__device__ __forceinline__ int xcd_swz(int id, int n) {
  const int q = n >> 3, r = n & 7;
  const int x = id & 7, k = id >> 3;
  return (x < r ? x * (q + 1) : r * (q + 1) + (x - r) * q) + k;
}

// ---------------------------------------------------------------------------
// 256x256 GEMM core, BK=64, 8 waves (2M x 4N), ONE barrier per K-tile.
//   acc[mi][ni] = transposed fragments: D = mfma(bF, aF) -> rows=n, cols=t.
// A is TRIPLE-buffered (3 x 32 KiB slots): read slot t%3, stage A(t+2) into
//   slot (t+2)%3 — disjoint from the live-read slot (t%3) and the landed
//   slot ((t+1)%3). Last reader of slot (t+2)%3 was tile t-1, whose reads
//   complete (lgkm before its MFMAs) ahead of the t-1 boundary barrier ->
//   WAR-safe with NO intra-tile fence. B double-buffered as in r5 (B(t+1)
//   stage targets the slot last read in tile t-1, same fence). 160 KiB LDS
//   total (AITER fmha precedent on gfx950, m243).
// vmcnt ledger (r5-verified): per tile issue B(t+1) then A(t+2) (8 loads).
//   Boundary vmcnt(4): FIFO [A(t+1),B(t+1),A(t+2)] -> drains tile t+1's
//   needs, keeps A(t+2) in flight. Tail t>=NT-2: vmcnt(0).
// Prologue: A0,B0,A1 (12 loads); vmcnt(4) -> tile0 landed; BAR.
// LDS swizzle: 16B block, phys = logical ^ (row&7), via pre-swizzled global
// source (involution both sides, rule #21). Verified 0 bank conflicts (r4-r7).
// ---------------------------------------------------------------------------
__device__ __forceinline__ void gemm256(
    const __bf16* __restrict__ aT, const __bf16* __restrict__ bT, const int K,
    __bf16 (*Ab)[2][128][64],   // 3 slots
    __bf16 (*Bb)[2][128][64],   // 2 slots
    f32x4 (&acc)[8][4]) {
  const int tid = threadIdx.x;
  const int lane = tid & 63, wid = tid >> 6;
  const int wr = wid >> 2, wcn = wid & 3;
  const int l8 = lane >> 3;
  const int colSwzE = (((lane & 7) ^ l8) << 3);  // pre-swizzled source col
  const int NT = K >> 6;

  int pblk[2];
  pblk[0] = (lane >> 4) ^ (lane & 7);
  pblk[1] = (4 + (lane >> 4)) ^ (lane & 7);

  bf16x8 aF[8][2];          // A frags cached across the whole tile
  bf16x8 bFa[2][2];         // B ni0-1
  bf16x8 bFb[2][2];         // B ni2-3

  auto STAGE_A = [&](int s, int slot) {
    if (s >= NT) return;
#pragma unroll
    for (int u = 0; u < 2; ++u) {
      const __bf16* src = aT + (size_t)(u * 128 + wid * 16 + l8) * K + s * 64 + colSwzE;
#pragma unroll
      for (int i = 0; i < 2; ++i)
        async16(&Ab[slot][u][wid * 16 + i * 8][0], src + (size_t)(i * 8) * K);
    }
  };
  auto STAGE_B = [&](int s) {
    if (s >= NT) return;
    const int slot = s & 1;
#pragma unroll
    for (int u = 0; u < 2; ++u) {
      const __bf16* src = bT + (size_t)(u * 128 + wid * 16 + l8) * K + s * 64 + colSwzE;
#pragma unroll
      for (int i = 0; i < 2; ++i)
        async16(&Bb[slot][u][wid * 16 + i * 8][0], src + (size_t)(i * 8) * K);
    }
  };

  // prologue: FIFO = [A0 x4, B0 x4, A1 x4]; vmcnt(4) -> A0,B0 landed.
  STAGE_A(0, 0);
  STAGE_B(0);
  STAGE_A(1, 1);
  asm volatile("s_waitcnt vmcnt(4)" ::: "memory");
  BARRIER();

  int rdA = 0, stA = 2;
  for (int t = 0; t < NT; ++t) {
    const char* pa = (const char*)&Ab[rdA][wr][0][0];
    const char* pb = (const char*)&Bb[t & 1][wcn >> 1][0][0];
    const int brow = (wcn & 1) * 64;

    // stage next tile's B (slot fenced by previous boundary barrier)
    STAGE_B(t + 1);

    // reads + MFMA: single barrier-free region; compiler interleaves.
#pragma unroll
    for (int mi = 0; mi < 4; ++mi)
#pragma unroll
      for (int kh = 0; kh < 2; ++kh)
        aF[mi][kh] = *(const bf16x8*)(pa + (mi * 16 + (lane & 15)) * 128 + pblk[kh] * 16);
#pragma unroll
    for (int ni = 0; ni < 2; ++ni)
#pragma unroll
      for (int kh = 0; kh < 2; ++kh)
        bFa[ni][kh] = *(const bf16x8*)(pb + (brow + ni * 16 + (lane & 15)) * 128 + pblk[kh] * 16);

    // stage A(t+2) into its own slot — no fence needed (triple buffer)
    STAGE_A(t + 2, stA);

    __builtin_amdgcn_s_setprio(1);
#pragma unroll
    for (int mi = 0; mi < 4; ++mi)
#pragma unroll
      for (int ni = 0; ni < 2; ++ni)
#pragma unroll
        for (int kh = 0; kh < 2; ++kh)
          acc[mi][ni] = __builtin_amdgcn_mfma_f32_16x16x32_bf16(bFa[ni][kh], aF[mi][kh], acc[mi][ni], 0, 0, 0);
    __builtin_amdgcn_s_setprio(0);

#pragma unroll
    for (int mi = 0; mi < 4; ++mi)
#pragma unroll
      for (int kh = 0; kh < 2; ++kh)
        aF[4 + mi][kh] = *(const bf16x8*)(pa + ((4 + mi) * 16 + (lane & 15)) * 128 + pblk[kh] * 16);

    __builtin_amdgcn_s_setprio(1);
#pragma unroll
    for (int mi = 0; mi < 4; ++mi)
#pragma unroll
      for (int ni = 0; ni < 2; ++ni)
#pragma unroll
        for (int kh = 0; kh < 2; ++kh)
          acc[4 + mi][ni] = __builtin_amdgcn_mfma_f32_16x16x32_bf16(bFa[ni][kh], aF[4 + mi][kh], acc[4 + mi][ni], 0, 0, 0);
    __builtin_amdgcn_s_setprio(0);

#pragma unroll
    for (int ni = 0; ni < 2; ++ni)
#pragma unroll
      for (int kh = 0; kh < 2; ++kh)
        bFb[ni][kh] = *(const bf16x8*)(pb + (brow + (2 + ni) * 16 + (lane & 15)) * 128 + pblk[kh] * 16);

    __builtin_amdgcn_s_setprio(1);
#pragma unroll
    for (int mi = 0; mi < 4; ++mi)
#pragma unroll
      for (int ni = 0; ni < 2; ++ni)
#pragma unroll
        for (int kh = 0; kh < 2; ++kh)
          acc[4 + mi][2 + ni] = __builtin_amdgcn_mfma_f32_16x16x32_bf16(bFb[ni][kh], aF[4 + mi][kh], acc[4 + mi][2 + ni], 0, 0, 0);
#pragma unroll
    for (int mi = 0; mi < 4; ++mi)
#pragma unroll
      for (int ni = 0; ni < 2; ++ni)
#pragma unroll
        for (int kh = 0; kh < 2; ++kh)
          acc[mi][2 + ni] = __builtin_amdgcn_mfma_f32_16x16x32_bf16(bFb[ni][kh], aF[mi][kh], acc[mi][2 + ni], 0, 0, 0);
    __builtin_amdgcn_s_setprio(0);

    if (t < NT - 2) { asm volatile("s_waitcnt vmcnt(4)" ::: "memory"); }
    else            { asm volatile("s_waitcnt vmcnt(0)" ::: "memory"); }
    BARRIER();   // sole barrier: tile t+1 landed; A(t+2) in flight
    rdA = (rdA == 2) ? 0 : rdA + 1;
    stA = (stA == 2) ? 0 : stA + 1;
  }
}

// ---------------------------------------------------------------------------
// fc1: h = relu(xb @ w1b^T + b1) -> bf16 hb.  acc is C^T: row=n, col=t.
// ---------------------------------------------------------------------------
__global__ __launch_bounds__(512, 2) void fc1g_kernel(
    const __bf16* __restrict__ xb, int eOffA,
    const __bf16* __restrict__ w1b, int eOffB,
    const float* __restrict__ b1, __bf16* __restrict__ hb,
    int e0, int t_base, int tcap, int nbT) {
  __shared__ __bf16 Ab[3][2][128][64];   // 96 KiB
  __shared__ __bf16 Bb[2][2][128][64];   // 64 KiB
  const int nbN = Hh / 256;  // 16
  const int id = xcd_swz(blockIdx.x, gridDim.x);
  const int z = id / (nbN * nbT);
  const int rm = id % (nbN * nbT);
  const int tblk = (rm / nbN) * 256, nblk = (rm % nbN) * 256;
  const int lane = threadIdx.x & 63, wid = threadIdx.x >> 6;
  const int wr = wid >> 2, wcn = wid & 3;

  const __bf16* aT = xb + ((size_t)(eOffA + z) * Tt + t_base + tblk) * Mm;
  const __bf16* bT = w1b + ((size_t)(eOffB + z) * Hh + nblk) * Mm;

  f32x4 acc[8][4];
#pragma unroll
  for (int i = 0; i < 8; ++i)
#pragma unroll
    for (int j = 0; j < 4; ++j) acc[i][j] = (f32x4){0.f, 0.f, 0.f, 0.f};

  gemm256(aT, bT, Mm, Ab, Bb, acc);

  const float* bias = b1 + (size_t)(e0 + z) * Hh;
#pragma unroll
  for (int ni = 0; ni < 4; ++ni) {
    const int n0 = nblk + wcn * 64 + ni * 16 + ((lane >> 4) << 2);
    const f32x4 b4 = *(const f32x4*)(bias + n0);
#pragma unroll
    for (int mi = 0; mi < 8; ++mi) {
      const int trow = tblk + wr * 128 + mi * 16 + (lane & 15);
      f32x4 v = acc[mi][ni];
      bf16x4 o;
#pragma unroll
      for (int rr = 0; rr < 4; ++rr) {
        float f = v[rr] + b4[rr];
        o[rr] = (__bf16)(f > 0.f ? f : 0.f);
      }
      *(bf16x4*)(hb + ((size_t)z * tcap + trow) * Hh + n0) = o;
    }
  }
}

// ---------------------------------------------------------------------------
// fc2: out = hb @ w2t^T + b2 -> fp32 scattered to [B,E,C,M]. acc: row=m, col=t.
// ---------------------------------------------------------------------------
__global__ __launch_bounds__(512, 2) void fc2g_kernel(
    const __bf16* __restrict__ hb, int tcap,
    const __bf16* __restrict__ w2t, int eOffB,
    const float* __restrict__ b2, float* __restrict__ out,
    int e0, int t_base, int nbT) {
  __shared__ __bf16 Ab[3][2][128][64];
  __shared__ __bf16 Bb[2][2][128][64];
  const int nbN = Mm / 256;  // 4
  const int id = xcd_swz(blockIdx.x, gridDim.x);
  const int z = id / (nbN * nbT);
  const int rm = id % (nbN * nbT);
  const int tblk = (rm / nbN) * 256, nblk = (rm % nbN) * 256;
  const int lane = threadIdx.x & 63, wid = threadIdx.x >> 6;
  const int wr = wid >> 2, wcn = wid & 3;
  const int e = e0 + z;

  const __bf16* aT = hb + ((size_t)z * tcap + tblk) * Hh;
  const __bf16* bT = w2t + ((size_t)(eOffB + z) * Mm + nblk) * Hh;

  f32x4 acc[8][4];
#pragma unroll
  for (int i = 0; i < 8; ++i)
#pragma unroll
    for (int j = 0; j < 4; ++j) acc[i][j] = (f32x4){0.f, 0.f, 0.f, 0.f};

  gemm256(aT, bT, Hh, Ab, Bb, acc);

  const float* bias = b2 + (size_t)e * Mm;
#pragma unroll
  for (int ni = 0; ni < 4; ++ni) {
    const int m0 = nblk + wcn * 64 + ni * 16 + ((lane >> 4) << 2);
    const f32x4 b4 = *(const f32x4*)(bias + m0);
#pragma unroll
    for (int mi = 0; mi < 8; ++mi) {
      const int t = t_base + tblk + wr * 128 + mi * 16 + (lane & 15);
      const int bb = t >> 9, cc = t & 511;
      f32x4 v = acc[mi][ni];
#pragma unroll
      for (int rr = 0; rr < 4; ++rr) v[rr] += b4[rr];
      *(f32x4*)(out + ((((size_t)bb * Ee + e) * Cc + cc) << 10) + m0) = v;
    }
  }
}

// ---------------------------------------------------------------------------
// Prepass: x [B,E,C,M] fp32 -> xb [z][T][M] bf16 (permute fused)
// ---------------------------------------------------------------------------
__global__ __launch_bounds__(256) void cvt_x_kernel(
    const float* __restrict__ x, __bf16* __restrict__ xb, int e0) {
  size_t idx8 = (size_t)blockIdx.x * 256 + threadIdx.x;
  int m8 = (int)(idx8 & 127);
  int t = (int)((idx8 >> 7) & 2047);
  int z = (int)(idx8 >> 18);
  int b = t >> 9, c = t & 511, e = e0 + z;
  const float* src = x + ((((size_t)b * Ee + e) * Cc + c) << 10) + (m8 << 3);
  f32x4 v0 = *(const f32x4*)src;
  f32x4 v1 = *(const f32x4*)(src + 4);
  bf16x8 o;
  o[0] = (__bf16)v0[0]; o[1] = (__bf16)v0[1]; o[2] = (__bf16)v0[2]; o[3] = (__bf16)v0[3];
  o[4] = (__bf16)v1[0]; o[5] = (__bf16)v1[1]; o[6] = (__bf16)v1[2]; o[7] = (__bf16)v1[3];
  *(bf16x8*)(xb + (idx8 << 3)) = o;
}

__global__ __launch_bounds__(256) void cvt_lin_kernel(
    const float* __restrict__ in, __bf16* __restrict__ outb) {
  size_t i8 = (size_t)blockIdx.x * 256 + threadIdx.x;
  const float* src = in + (i8 << 3);
  f32x4 v0 = *(const f32x4*)src;
  f32x4 v1 = *(const f32x4*)(src + 4);
  bf16x8 o;
  o[0] = (__bf16)v0[0]; o[1] = (__bf16)v0[1]; o[2] = (__bf16)v0[2]; o[3] = (__bf16)v0[3];
  o[4] = (__bf16)v1[0]; o[5] = (__bf16)v1[1]; o[6] = (__bf16)v1[2]; o[7] = (__bf16)v1[3];
  *(bf16x8*)(outb + (i8 << 3)) = o;
}

// ---------------------------------------------------------------------------
// Prepass: W2 [E][H][M] fp32 -> W2T [z][M][H] bf16 (transpose + convert)
// ---------------------------------------------------------------------------
__global__ __launch_bounds__(256) void tr_w2_kernel(
    const float* __restrict__ w2, __bf16* __restrict__ w2t, int e0) {
  __shared__ __bf16 tile[64][68];
  const int z = blockIdx.z, e = e0 + z;
  const int m0 = blockIdx.x * 64, h0 = blockIdx.y * 64;
  const int tid = threadIdx.x;
  const int cg = tid & 15, rg = tid >> 4;
#pragma unroll
  for (int p = 0; p < 4; ++p) {
    int hl = rg + p * 16;
    f32x4 v = *(const f32x4*)(w2 + (((size_t)e * Hh + h0 + hl) << 10) + m0 + (cg << 2));
#pragma unroll
    for (int i = 0; i < 4; ++i) tile[(cg << 2) + i][hl] = (__bf16)v[i];
  }
  __syncthreads();
#pragma unroll
  for (int p = 0; p < 4; ++p) {
    int ml = rg + p * 16;
    uint2 pk = *(const uint2*)(&tile[ml][cg << 2]);
    *(uint2*)(w2t + ((size_t)z * Mm + m0 + ml) * Hh + h0 + (cg << 2)) = pk;
  }
}

// ---------------------------------------------------------------------------
extern "C" void kernel_launch(void* const* d_in, const int* in_sizes, int n_in,
                              void* d_out, int out_size, void* d_ws, size_t ws_size,
                              hipStream_t stream) {
  const float* x  = (const float*)d_in[0];
  const float* w1 = (const float*)d_in[1];
  const float* b1 = (const float*)d_in[2];
  const float* w2 = (const float*)d_in[3];
  const float* b2 = (const float*)d_in[4];
  float* out = (float*)d_out;

  const size_t xbS = (size_t)Tt * Mm * 2;  //  4 MiB / expert
  const size_t w1S = (size_t)Hh * Mm * 2;  //  8 MiB / expert
  const size_t w2S = (size_t)Mm * Hh * 2;  //  8 MiB / expert
  const size_t hbS = (size_t)Tt * Hh * 2;  // 16 MiB / expert
  char* ws = (char*)d_ws;

  if (ws_size >= Ee * (xbS + w1S + w2S) + 4 * hbS) {
    // Path A: conversions resident; GEMMs interleaved in groups of 4 so the
    // 64 MiB hb region stays L3-hot between fc1 and fc2 (same region reused).
    __bf16* xb  = (__bf16*)ws;
    __bf16* w1b = (__bf16*)(ws + Ee * xbS);
    __bf16* w2t = (__bf16*)(ws + Ee * (xbS + w1S));
    __bf16* hb  = (__bf16*)(ws + Ee * (xbS + w1S + w2S));
    cvt_x_kernel<<<Ee * 1024, 256, 0, stream>>>(x, xb, 0);
    cvt_lin_kernel<<<Ee * 2048, 256, 0, stream>>>(w1, w1b);
    tr_w2_kernel<<<dim3(Mm / 64, Hh / 64, Ee), 256, 0, stream>>>(w2, w2t, 0);
    for (int e0 = 0; e0 < Ee; e0 += 4) {
      fc1g_kernel<<<(Hh / 256) * (Tt / 256) * 4, 512, 0, stream>>>(xb, e0, w1b, e0, b1, hb, e0, 0, Tt, Tt / 256);
      fc2g_kernel<<<(Mm / 256) * (Tt / 256) * 4, 512, 0, stream>>>(hb, Tt, w2t, e0, b2, out, e0, 0, Tt / 256);
    }
  } else if (ws_size >= Ee * (xbS + w1S + w2S) + hbS) {
    // Path B: all conversions resident; hb grouped (1-3 experts).
    __bf16* xb  = (__bf16*)ws;
    __bf16* w1b = (__bf16*)(ws + Ee * xbS);
    __bf16* w2t = (__bf16*)(ws + Ee * (xbS + w1S));
    __bf16* hb  = (__bf16*)(ws + Ee * (xbS + w1S + w2S));
    int Gh = (int)((ws_size - Ee * (xbS + w1S + w2S)) / hbS);
    if (Gh > Ee) Gh = Ee;
    cvt_x_kernel<<<Ee * 1024, 256, 0, stream>>>(x, xb, 0);
    cvt_lin_kernel<<<Ee * 2048, 256, 0, stream>>>(w1, w1b);
    tr_w2_kernel<<<dim3(Mm / 64, Hh / 64, Ee), 256, 0, stream>>>(w2, w2t, 0);
    for (int e0 = 0; e0 < Ee; e0 += Gh) {
      int g = (Ee - e0) < Gh ? (Ee - e0) : Gh;
      fc1g_kernel<<<(Hh / 256) * (Tt / 256) * g, 512, 0, stream>>>(xb, e0, w1b, e0, b1, hb, e0, 0, Tt, Tt / 256);
      fc2g_kernel<<<(Mm / 256) * (Tt / 256) * g, 512, 0, stream>>>(hb, Tt, w2t, e0, b2, out, e0, 0, Tt / 256);
    }
  } else if (ws_size >= xbS + w1S + w2S + hbS) {
    // Path C: full pipeline grouped by G experts.
    int G = (int)(ws_size / (xbS + w1S + w2S + hbS));
    if (G > Ee) G = Ee;
    __bf16* xb  = (__bf16*)ws;
    __bf16* w1b = (__bf16*)(ws + (size_t)G * xbS);
    __bf16* w2t = (__bf16*)(ws + (size_t)G * (xbS + w1S));
    __bf16* hb  = (__bf16*)(ws + (size_t)G * (xbS + w1S + w2S));
    for (int e0 = 0; e0 < Ee; e0 += G) {
      int g = (Ee - e0) < G ? (Ee - e0) : G;
      cvt_x_kernel<<<g * 1024, 256, 0, stream>>>(x, xb, e0);
      cvt_lin_kernel<<<g * 2048, 256, 0, stream>>>(w1 + (size_t)e0 * Hh * Mm, w1b);
      tr_w2_kernel<<<dim3(Mm / 64, Hh / 64, g), 256, 0, stream>>>(w2, w2t, e0);
      fc1g_kernel<<<(Hh / 256) * (Tt / 256) * g, 512, 0, stream>>>(xb, 0, w1b, 0, b1, hb, e0, 0, Tt, Tt / 256);
      fc2g_kernel<<<(Mm / 256) * (Tt / 256) * g, 512, 0, stream>>>(hb, Tt, w2t, 0, b2, out, e0, 0, Tt / 256);
    }
  } else {
    // Path D: one expert, T chunked (256-row granularity).
    __bf16* xb  = (__bf16*)ws;
    __bf16* w1b = (__bf16*)(ws + xbS);
    __bf16* w2t = (__bf16*)(ws + xbS + w1S);
    __bf16* hb  = (__bf16*)(ws + xbS + w1S + w2S);
    size_t rem = ws_size > (xbS + w1S + w2S) ? ws_size - (xbS + w1S + w2S) : 0;
    int Tc = (int)(rem / ((size_t)Hh * 2)) & ~255;
    if (Tc > Tt) Tc = Tt;
    if (Tc < 256) Tc = 256;
    for (int e0 = 0; e0 < Ee; ++e0) {
      cvt_x_kernel<<<1024, 256, 0, stream>>>(x, xb, e0);
      cvt_lin_kernel<<<2048, 256, 0, stream>>>(w1 + (size_t)e0 * Hh * Mm, w1b);
      tr_w2_kernel<<<dim3(Mm / 64, Hh / 64, 1), 256, 0, stream>>>(w2, w2t, e0);
      for (int t0 = 0; t0 < Tt; t0 += Tc) {
        int tc = (Tt - t0) < Tc ? (Tt - t0) : Tc;
        fc1g_kernel<<<(Hh / 256) * (tc / 256), 512, 0, stream>>>(xb, 0, w1b, 0, b1, hb, e0, t0, Tc, tc / 256);
        fc2g_kernel<<<(Mm / 256) * (tc / 256), 512, 0, stream>>>(hb, Tc, w2t, 0, b2, out, e0, t0, tc / 256);
      }
    }
  }
}

// Round 10
// 428.494 us; speedup vs baseline: 1.3006x; 1.3006x over previous
//
#include <hip/hip_runtime.h>
#include <hip/hip_bf16.h>

typedef __bf16 bf16x8 __attribute__((ext_vector_type(8)));
typedef __bf16 bf16x4 __attribute__((ext_vector_type(4)));
typedef float  f32x4  __attribute__((ext_vector_type(4)));

constexpr int Ee = 8, Cc = 512, Mm = 1024, Hh = 4096, Tt = 2048;

// async global->LDS, 16B/lane. LDS dest wave-uniform base + lane*16 (m97/m104).
__device__ __forceinline__ void async16(void* lds, const void* g) {
  __builtin_amdgcn_global_load_lds(
      (const __attribute__((address_space(1))) void*)g,
      (__attribute__((address_space(3))) void*)lds, 16, 0, 0);
}

#define FENCE() asm volatile("" ::: "memory")
#define BARRIER() do { FENCE(); __builtin_amdgcn_s_barrier(); FENCE(); } while (0)

// Bijective XCD-chunked swizzle (m204).
__device__ __forceinline__ int xcd_swz(int id, int n) {
  const int q = n >> 3, r = n & 7;
  const int x = id & 7, k = id >> 3;
  return (x < r ? x * (q + 1) : r * (q + 1) + (x - r) * q) + k;
}

// ---------------------------------------------------------------------------
// 256x256 GEMM core, BK=64, 8 waves (2M x 4N), ONE barrier per K-tile.
//   acc[mi][ni] = transposed fragments: D = mfma(bF, aF) -> rows=n, cols=t.
// A TRIPLE-buffered (3 slots): read t%3, stage A(t+2) into (t+2)%3 — disjoint
//   from live (t%3) and landed ((t+1)%3); last reader of (t+2)%3 was tile
//   t-1, fenced by that tile's boundary barrier. WAR-safe, no intra-tile
//   fence. B double-buffered (B(t+1) targets the slot last read in t-1).
//   160 KiB LDS (AITER fmha precedent, m243). [r8: correctness-proven]
// vmcnt ledger (r5-verified): per tile issue B(t+1)x4 then A(t+2)x4.
//   Boundary vmcnt(4): FIFO [A(t+1),B(t+1),A(t+2)] -> drains tile t+1,
//   keeps A(t+2) in flight. Tail t>=NT-2: vmcnt(0).
// Prologue: A0,B0,A1 (12 loads); vmcnt(4) -> tile0 landed; BAR.
// LDS swizzle: 16B block, phys = logical ^ (row&7), via pre-swizzled global
// source (involution both sides, rule #21). 0 bank conflicts (r4-r8).
// ---------------------------------------------------------------------------
__device__ __forceinline__ void gemm256(
    const __bf16* __restrict__ aT, const __bf16* __restrict__ bT, const int K,
    __bf16 (*Ab)[2][128][64],   // 3 slots
    __bf16 (*Bb)[2][128][64],   // 2 slots
    f32x4 (&acc)[8][4]) {
  const int tid = threadIdx.x;
  const int lane = tid & 63, wid = tid >> 6;
  const int wr = wid >> 2, wcn = wid & 3;
  const int l8 = lane >> 3;
  const int colSwzE = (((lane & 7) ^ l8) << 3);  // pre-swizzled source col
  const int NT = K >> 6;

  int pblk[2];
  pblk[0] = (lane >> 4) ^ (lane & 7);
  pblk[1] = (4 + (lane >> 4)) ^ (lane & 7);

  bf16x8 aF[8][2];          // A frags cached across the whole tile
  bf16x8 bFa[2][2];         // B ni0-1
  bf16x8 bFb[2][2];         // B ni2-3

  auto STAGE_A = [&](int s, int slot) {
    if (s >= NT) return;
#pragma unroll
    for (int u = 0; u < 2; ++u) {
      const __bf16* src = aT + (size_t)(u * 128 + wid * 16 + l8) * K + s * 64 + colSwzE;
#pragma unroll
      for (int i = 0; i < 2; ++i)
        async16(&Ab[slot][u][wid * 16 + i * 8][0], src + (size_t)(i * 8) * K);
    }
  };
  auto STAGE_B = [&](int s) {
    if (s >= NT) return;
    const int slot = s & 1;
#pragma unroll
    for (int u = 0; u < 2; ++u) {
      const __bf16* src = bT + (size_t)(u * 128 + wid * 16 + l8) * K + s * 64 + colSwzE;
#pragma unroll
      for (int i = 0; i < 2; ++i)
        async16(&Bb[slot][u][wid * 16 + i * 8][0], src + (size_t)(i * 8) * K);
    }
  };

  // prologue: FIFO = [A0 x4, B0 x4, A1 x4]; vmcnt(4) -> A0,B0 landed.
  STAGE_A(0, 0);
  STAGE_B(0);
  STAGE_A(1, 1);
  asm volatile("s_waitcnt vmcnt(4)" ::: "memory");
  BARRIER();

  int rdA = 0, stA = 2;
  for (int t = 0; t < NT; ++t) {
    const char* pa = (const char*)&Ab[rdA][wr][0][0];
    const char* pb = (const char*)&Bb[t & 1][wcn >> 1][0][0];
    const int brow = (wcn & 1) * 64;

    // stage next tile's B (slot fenced by previous boundary barrier)
    STAGE_B(t + 1);

    // reads + MFMA: single barrier-free region; compiler interleaves.
#pragma unroll
    for (int mi = 0; mi < 4; ++mi)
#pragma unroll
      for (int kh = 0; kh < 2; ++kh)
        aF[mi][kh] = *(const bf16x8*)(pa + (mi * 16 + (lane & 15)) * 128 + pblk[kh] * 16);
#pragma unroll
    for (int ni = 0; ni < 2; ++ni)
#pragma unroll
      for (int kh = 0; kh < 2; ++kh)
        bFa[ni][kh] = *(const bf16x8*)(pb + (brow + ni * 16 + (lane & 15)) * 128 + pblk[kh] * 16);

    // stage A(t+2) into its own slot — no fence needed (triple buffer)
    STAGE_A(t + 2, stA);

    __builtin_amdgcn_s_setprio(1);
#pragma unroll
    for (int mi = 0; mi < 4; ++mi)
#pragma unroll
      for (int ni = 0; ni < 2; ++ni)
#pragma unroll
        for (int kh = 0; kh < 2; ++kh)
          acc[mi][ni] = __builtin_amdgcn_mfma_f32_16x16x32_bf16(bFa[ni][kh], aF[mi][kh], acc[mi][ni], 0, 0, 0);
    __builtin_amdgcn_s_setprio(0);

#pragma unroll
    for (int mi = 0; mi < 4; ++mi)
#pragma unroll
      for (int kh = 0; kh < 2; ++kh)
        aF[4 + mi][kh] = *(const bf16x8*)(pa + ((4 + mi) * 16 + (lane & 15)) * 128 + pblk[kh] * 16);

    __builtin_amdgcn_s_setprio(1);
#pragma unroll
    for (int mi = 0; mi < 4; ++mi)
#pragma unroll
      for (int ni = 0; ni < 2; ++ni)
#pragma unroll
        for (int kh = 0; kh < 2; ++kh)
          acc[4 + mi][ni] = __builtin_amdgcn_mfma_f32_16x16x32_bf16(bFa[ni][kh], aF[4 + mi][kh], acc[4 + mi][ni], 0, 0, 0);
    __builtin_amdgcn_s_setprio(0);

#pragma unroll
    for (int ni = 0; ni < 2; ++ni)
#pragma unroll
      for (int kh = 0; kh < 2; ++kh)
        bFb[ni][kh] = *(const bf16x8*)(pb + (brow + (2 + ni) * 16 + (lane & 15)) * 128 + pblk[kh] * 16);

    __builtin_amdgcn_s_setprio(1);
#pragma unroll
    for (int mi = 0; mi < 4; ++mi)
#pragma unroll
      for (int ni = 0; ni < 2; ++ni)
#pragma unroll
        for (int kh = 0; kh < 2; ++kh)
          acc[4 + mi][2 + ni] = __builtin_amdgcn_mfma_f32_16x16x32_bf16(bFb[ni][kh], aF[4 + mi][kh], acc[4 + mi][2 + ni], 0, 0, 0);
#pragma unroll
    for (int mi = 0; mi < 4; ++mi)
#pragma unroll
      for (int ni = 0; ni < 2; ++ni)
#pragma unroll
        for (int kh = 0; kh < 2; ++kh)
          acc[mi][2 + ni] = __builtin_amdgcn_mfma_f32_16x16x32_bf16(bFb[ni][kh], aF[mi][kh], acc[mi][2 + ni], 0, 0, 0);
    __builtin_amdgcn_s_setprio(0);

    if (t < NT - 2) { asm volatile("s_waitcnt vmcnt(4)" ::: "memory"); }
    else            { asm volatile("s_waitcnt vmcnt(0)" ::: "memory"); }
    BARRIER();   // sole barrier: tile t+1 landed; A(t+2) in flight
    rdA = (rdA == 2) ? 0 : rdA + 1;
    stA = (stA == 2) ? 0 : stA + 1;
  }
}

// ---------------------------------------------------------------------------
// fc1: h = relu(xb @ w1b^T + b1) -> bf16 hb.  acc is C^T: row=n, col=t.
// ---------------------------------------------------------------------------
__global__ __launch_bounds__(512, 2) void fc1g_kernel(
    const __bf16* __restrict__ xb, int eOffA,
    const __bf16* __restrict__ w1b, int eOffB,
    const float* __restrict__ b1, __bf16* __restrict__ hb,
    int e0, int t_base, int tcap, int nbT) {
  __shared__ __bf16 Ab[3][2][128][64];   // 96 KiB
  __shared__ __bf16 Bb[2][2][128][64];   // 64 KiB
  const int nbN = Hh / 256;  // 16
  const int id = xcd_swz(blockIdx.x, gridDim.x);
  const int z = id / (nbN * nbT);
  const int rm = id % (nbN * nbT);
  const int tblk = (rm / nbN) * 256, nblk = (rm % nbN) * 256;
  const int lane = threadIdx.x & 63, wid = threadIdx.x >> 6;
  const int wr = wid >> 2, wcn = wid & 3;

  const __bf16* aT = xb + ((size_t)(eOffA + z) * Tt + t_base + tblk) * Mm;
  const __bf16* bT = w1b + ((size_t)(eOffB + z) * Hh + nblk) * Mm;

  f32x4 acc[8][4];
#pragma unroll
  for (int i = 0; i < 8; ++i)
#pragma unroll
    for (int j = 0; j < 4; ++j) acc[i][j] = (f32x4){0.f, 0.f, 0.f, 0.f};

  gemm256(aT, bT, Mm, Ab, Bb, acc);

  const float* bias = b1 + (size_t)(e0 + z) * Hh;
#pragma unroll
  for (int ni = 0; ni < 4; ++ni) {
    const int n0 = nblk + wcn * 64 + ni * 16 + ((lane >> 4) << 2);
    const f32x4 b4 = *(const f32x4*)(bias + n0);
#pragma unroll
    for (int mi = 0; mi < 8; ++mi) {
      const int trow = tblk + wr * 128 + mi * 16 + (lane & 15);
      f32x4 v = acc[mi][ni];
      bf16x4 o;
#pragma unroll
      for (int rr = 0; rr < 4; ++rr) {
        float f = v[rr] + b4[rr];
        o[rr] = (__bf16)(f > 0.f ? f : 0.f);
      }
      *(bf16x4*)(hb + ((size_t)z * tcap + trow) * Hh + n0) = o;
    }
  }
}

// ---------------------------------------------------------------------------
// fc2: out = hb @ w2t^T + b2 -> fp32 scattered to [B,E,C,M]. acc: row=m, col=t.
// ---------------------------------------------------------------------------
__global__ __launch_bounds__(512, 2) void fc2g_kernel(
    const __bf16* __restrict__ hb, int tcap,
    const __bf16* __restrict__ w2t, int eOffB,
    const float* __restrict__ b2, float* __restrict__ out,
    int e0, int t_base, int nbT) {
  __shared__ __bf16 Ab[3][2][128][64];
  __shared__ __bf16 Bb[2][2][128][64];
  const int nbN = Mm / 256;  // 4
  const int id = xcd_swz(blockIdx.x, gridDim.x);
  const int z = id / (nbN * nbT);
  const int rm = id % (nbN * nbT);
  const int tblk = (rm / nbN) * 256, nblk = (rm % nbN) * 256;
  const int lane = threadIdx.x & 63, wid = threadIdx.x >> 6;
  const int wr = wid >> 2, wcn = wid & 3;
  const int e = e0 + z;

  const __bf16* aT = hb + ((size_t)z * tcap + tblk) * Hh;
  const __bf16* bT = w2t + ((size_t)(eOffB + z) * Mm + nblk) * Hh;

  f32x4 acc[8][4];
#pragma unroll
  for (int i = 0; i < 8; ++i)
#pragma unroll
    for (int j = 0; j < 4; ++j) acc[i][j] = (f32x4){0.f, 0.f, 0.f, 0.f};

  gemm256(aT, bT, Hh, Ab, Bb, acc);

  const float* bias = b2 + (size_t)e * Mm;
#pragma unroll
  for (int ni = 0; ni < 4; ++ni) {
    const int m0 = nblk + wcn * 64 + ni * 16 + ((lane >> 4) << 2);
    const f32x4 b4 = *(const f32x4*)(bias + m0);
#pragma unroll
    for (int mi = 0; mi < 8; ++mi) {
      const int t = t_base + tblk + wr * 128 + mi * 16 + (lane & 15);
      const int bb = t >> 9, cc = t & 511;
      f32x4 v = acc[mi][ni];
#pragma unroll
      for (int rr = 0; rr < 4; ++rr) v[rr] += b4[rr];
      *(f32x4*)(out + ((((size_t)bb * Ee + e) * Cc + cc) << 10) + m0) = v;
    }
  }
}

// ---------------------------------------------------------------------------
// Prepass: x [B,E,C,M] fp32 -> xb [z][T][M] bf16 (permute fused)
// ---------------------------------------------------------------------------
__global__ __launch_bounds__(256) void cvt_x_kernel(
    const float* __restrict__ x, __bf16* __restrict__ xb, int e0) {
  size_t idx8 = (size_t)blockIdx.x * 256 + threadIdx.x;
  int m8 = (int)(idx8 & 127);
  int t = (int)((idx8 >> 7) & 2047);
  int z = (int)(idx8 >> 18);
  int b = t >> 9, c = t & 511, e = e0 + z;
  const float* src = x + ((((size_t)b * Ee + e) * Cc + c) << 10) + (m8 << 3);
  f32x4 v0 = *(const f32x4*)src;
  f32x4 v1 = *(const f32x4*)(src + 4);
  bf16x8 o;
  o[0] = (__bf16)v0[0]; o[1] = (__bf16)v0[1]; o[2] = (__bf16)v0[2]; o[3] = (__bf16)v0[3];
  o[4] = (__bf16)v1[0]; o[5] = (__bf16)v1[1]; o[6] = (__bf16)v1[2]; o[7] = (__bf16)v1[3];
  *(bf16x8*)(xb + (idx8 << 3)) = o;
}

__global__ __launch_bounds__(256) void cvt_lin_kernel(
    const float* __restrict__ in, __bf16* __restrict__ outb) {
  size_t i8 = (size_t)blockIdx.x * 256 + threadIdx.x;
  const float* src = in + (i8 << 3);
  f32x4 v0 = *(const f32x4*)src;
  f32x4 v1 = *(const f32x4*)(src + 4);
  bf16x8 o;
  o[0] = (__bf16)v0[0]; o[1] = (__bf16)v0[1]; o[2] = (__bf16)v0[2]; o[3] = (__bf16)v0[3];
  o[4] = (__bf16)v1[0]; o[5] = (__bf16)v1[1]; o[6] = (__bf16)v1[2]; o[7] = (__bf16)v1[3];
  *(bf16x8*)(outb + (i8 << 3)) = o;
}

// ---------------------------------------------------------------------------
// Prepass: W2 [E][H][M] fp32 -> W2T [z][M][H] bf16 (transpose + convert)
// ---------------------------------------------------------------------------
__global__ __launch_bounds__(256) void tr_w2_kernel(
    const float* __restrict__ w2, __bf16* __restrict__ w2t, int e0) {
  __shared__ __bf16 tile[64][68];
  const int z = blockIdx.z, e = e0 + z;
  const int m0 = blockIdx.x * 64, h0 = blockIdx.y * 64;
  const int tid = threadIdx.x;
  const int cg = tid & 15, rg = tid >> 4;
#pragma unroll
  for (int p = 0; p < 4; ++p) {
    int hl = rg + p * 16;
    f32x4 v = *(const f32x4*)(w2 + (((size_t)e * Hh + h0 + hl) << 10) + m0 + (cg << 2));
#pragma unroll
    for (int i = 0; i < 4; ++i) tile[(cg << 2) + i][hl] = (__bf16)v[i];
  }
  __syncthreads();
#pragma unroll
  for (int p = 0; p < 4; ++p) {
    int ml = rg + p * 16;
    uint2 pk = *(const uint2*)(&tile[ml][cg << 2]);
    *(uint2*)(w2t + ((size_t)z * Mm + m0 + ml) * Hh + h0 + (cg << 2)) = pk;
  }
}

// ---------------------------------------------------------------------------
extern "C" void kernel_launch(void* const* d_in, const int* in_sizes, int n_in,
                              void* d_out, int out_size, void* d_ws, size_t ws_size,
                              hipStream_t stream) {
  const float* x  = (const float*)d_in[0];
  const float* w1 = (const float*)d_in[1];
  const float* b1 = (const float*)d_in[2];
  const float* w2 = (const float*)d_in[3];
  const float* b2 = (const float*)d_in[4];
  float* out = (float*)d_out;

  const size_t xbS = (size_t)Tt * Mm * 2;  //  4 MiB / expert
  const size_t w1S = (size_t)Hh * Mm * 2;  //  8 MiB / expert
  const size_t w2S = (size_t)Mm * Hh * 2;  //  8 MiB / expert
  const size_t hbS = (size_t)Tt * Hh * 2;  // 16 MiB / expert
  char* ws = (char*)d_ws;

  if (ws_size >= Ee * (xbS + w1S + w2S + hbS)) {
    // Path A: everything resident (288 MiB). Full-width dispatches:
    // fc1 = 1024 blocks (4 rounds/CU), fc2 = 256 blocks (1/CU).
    __bf16* xb  = (__bf16*)ws;
    __bf16* w1b = (__bf16*)(ws + Ee * xbS);
    __bf16* w2t = (__bf16*)(ws + Ee * (xbS + w1S));
    __bf16* hb  = (__bf16*)(ws + Ee * (xbS + w1S + w2S));
    cvt_x_kernel<<<Ee * 1024, 256, 0, stream>>>(x, xb, 0);
    cvt_lin_kernel<<<Ee * 2048, 256, 0, stream>>>(w1, w1b);
    tr_w2_kernel<<<dim3(Mm / 64, Hh / 64, Ee), 256, 0, stream>>>(w2, w2t, 0);
    fc1g_kernel<<<(Hh / 256) * (Tt / 256) * Ee, 512, 0, stream>>>(xb, 0, w1b, 0, b1, hb, 0, 0, Tt, Tt / 256);
    fc2g_kernel<<<(Mm / 256) * (Tt / 256) * Ee, 512, 0, stream>>>(hb, Tt, w2t, 0, b2, out, 0, 0, Tt / 256);
  } else if (ws_size >= Ee * (xbS + w1S + w2S) + hbS) {
    // Path B: all conversions resident; hb grouped.
    __bf16* xb  = (__bf16*)ws;
    __bf16* w1b = (__bf16*)(ws + Ee * xbS);
    __bf16* w2t = (__bf16*)(ws + Ee * (xbS + w1S));
    __bf16* hb  = (__bf16*)(ws + Ee * (xbS + w1S + w2S));
    int Gh = (int)((ws_size - Ee * (xbS + w1S + w2S)) / hbS);
    if (Gh > Ee) Gh = Ee;
    cvt_x_kernel<<<Ee * 1024, 256, 0, stream>>>(x, xb, 0);
    cvt_lin_kernel<<<Ee * 2048, 256, 0, stream>>>(w1, w1b);
    tr_w2_kernel<<<dim3(Mm / 64, Hh / 64, Ee), 256, 0, stream>>>(w2, w2t, 0);
    for (int e0 = 0; e0 < Ee; e0 += Gh) {
      int g = (Ee - e0) < Gh ? (Ee - e0) : Gh;
      fc1g_kernel<<<(Hh / 256) * (Tt / 256) * g, 512, 0, stream>>>(xb, e0, w1b, e0, b1, hb, e0, 0, Tt, Tt / 256);
      fc2g_kernel<<<(Mm / 256) * (Tt / 256) * g, 512, 0, stream>>>(hb, Tt, w2t, e0, b2, out, e0, 0, Tt / 256);
    }
  } else if (ws_size >= xbS + w1S + w2S + hbS) {
    // Path C: full pipeline grouped by G experts.
    int G = (int)(ws_size / (xbS + w1S + w2S + hbS));
    if (G > Ee) G = Ee;
    __bf16* xb  = (__bf16*)ws;
    __bf16* w1b = (__bf16*)(ws + (size_t)G * xbS);
    __bf16* w2t = (__bf16*)(ws + (size_t)G * (xbS + w1S));
    __bf16* hb  = (__bf16*)(ws + (size_t)G * (xbS + w1S + w2S));
    for (int e0 = 0; e0 < Ee; e0 += G) {
      int g = (Ee - e0) < G ? (Ee - e0) : G;
      cvt_x_kernel<<<g * 1024, 256, 0, stream>>>(x, xb, e0);
      cvt_lin_kernel<<<g * 2048, 256, 0, stream>>>(w1 + (size_t)e0 * Hh * Mm, w1b);
      tr_w2_kernel<<<dim3(Mm / 64, Hh / 64, g), 256, 0, stream>>>(w2, w2t, e0);
      fc1g_kernel<<<(Hh / 256) * (Tt / 256) * g, 512, 0, stream>>>(xb, 0, w1b, 0, b1, hb, e0, 0, Tt, Tt / 256);
      fc2g_kernel<<<(Mm / 256) * (Tt / 256) * g, 512, 0, stream>>>(hb, Tt, w2t, 0, b2, out, e0, 0, Tt / 256);
    }
  } else {
    // Path D: one expert, T chunked (256-row granularity).
    __bf16* xb  = (__bf16*)ws;
    __bf16* w1b = (__bf16*)(ws + xbS);
    __bf16* w2t = (__bf16*)(ws + xbS + w1S);
    __bf16* hb  = (__bf16*)(ws + xbS + w1S + w2S);
    size_t rem = ws_size > (xbS + w1S + w2S) ? ws_size - (xbS + w1S + w2S) : 0;
    int Tc = (int)(rem / ((size_t)Hh * 2)) & ~255;
    if (Tc > Tt) Tc = Tt;
    if (Tc < 256) Tc = 256;
    for (int e0 = 0; e0 < Ee; ++e0) {
      cvt_x_kernel<<<1024, 256, 0, stream>>>(x, xb, e0);
      cvt_lin_kernel<<<2048, 256, 0, stream>>>(w1 + (size_t)e0 * Hh * Mm, w1b);
      tr_w2_kernel<<<dim3(Mm / 64, Hh / 64, 1), 256, 0, stream>>>(w2, w2t, e0);
      for (int t0 = 0; t0 < Tt; t0 += Tc) {
        int tc = (Tt - t0) < Tc ? (Tt - t0) : Tc;
        fc1g_kernel<<<(Hh / 256) * (tc / 256), 512, 0, stream>>>(xb, 0, w1b, 0, b1, hb, e0, t0, Tc, tc / 256);
        fc2g_kernel<<<(Mm / 256) * (tc / 256), 512, 0, stream>>>(hb, Tc, w2t, 0, b2, out, e0, t0, tc / 256);
      }
    }
  }
}